// Round 13
// baseline (1739.815 us; speedup 1.0000x reference)
//
#include <hip/hip_runtime.h>
#include <hip/hip_fp16.h>

#define T_SEQ   2048
#define HID     50
#define UPAD    64      // unit padding (type-major: n = ty*64 + u)
#define NPAD    256     // 4 types * 64
#define KPAD    64      // h padded 50 -> 64 (K = 2 MFMAs of 32)
#define NBLK    1024    // one wave per TWO batch rows (chains P,Q interleaved)
#define VOC     13

typedef __attribute__((ext_vector_type(8))) _Float16 half8;
typedef __attribute__((ext_vector_type(4))) float    f32x4;

__device__ __forceinline__ ushort f16b(float f) {
    return __half_as_ushort(__float2half(f));   // RNE
}
__device__ __forceinline__ float h2f(ushort h) {
    return __half2float(__ushort_as_half(h));
}
__device__ __forceinline__ float rcp_(float x) { return __builtin_amdgcn_rcpf(x); }
__device__ __forceinline__ float sigm(float x) { return rcp_(1.f + __expf(-x)); }
__device__ __forceinline__ float tanh_(float x) {
    return fmaf(2.f, rcp_(1.f + __expf(-2.f * x)), -1.f);
}

// Bmat[n][k], n = ty*64+u: W_hh[ty*50+u][k] (u<50, k<50), else 0.  f16 bits.
__global__ void build_B(const float* __restrict__ Whh, ushort* __restrict__ B) {
    int idx = blockIdx.x * blockDim.x + threadIdx.x;
    if (idx >= NPAD * KPAD) return;
    int n = idx >> 6, k = idx & 63;
    int ty = n >> 6, u = n & 63;
    B[idx] = (u < HID && k < HID) ? f16b(Whh[(ty * HID + u) * HID + k]) : (ushort)0;
}

// Tt[v][u] = ushort4{ f16(T(v,ty,u)) : ty=0..3 },
// T(v,ty,u) = sum_e embed[v,e]*W_ih[ty*50+u, e] + b_ih[g] + b_hh[g]  (u<50 else 0)
__global__ void build_T(const float* __restrict__ embed,
                        const float* __restrict__ Wih,
                        const float* __restrict__ bih,
                        const float* __restrict__ bhh,
                        ushort4* __restrict__ Tt) {
    int idx = blockIdx.x * blockDim.x + threadIdx.x;   // over 13*64
    if (idx >= VOC * UPAD) return;
    int v = idx >> 6, u = idx & 63;
    ushort4 r = {0, 0, 0, 0};
    if (u < HID) {
        ushort vals[4];
        for (int ty = 0; ty < 4; ++ty) {
            int g = ty * HID + u;
            float t = bih[g] + bhh[g];
            for (int e = 0; e < HID; ++e)
                t = fmaf(embed[v * HID + e], Wih[g * HID + e], t);
            vals[ty] = f16b(t);
        }
        r.x = vals[0]; r.y = vals[1]; r.z = vals[2]; r.w = vals[3];
    }
    Tt[idx] = r;
}

#define ISSUE_MFMA(Z, A0, A1)                                                     \
    _Pragma("unroll")                                                             \
    for (int ty = 0; ty < 4; ++ty) {                                              \
        _Pragma("unroll")                                                         \
        for (int j = 0; j < 4; ++j) {                                             \
            f32x4 t0 = __builtin_amdgcn_mfma_f32_16x16x32_f16(A0, bf[ty][j][0],   \
                                                              zc, 0, 0, 0);      \
            Z[ty][j] = __builtin_amdgcn_mfma_f32_16x16x32_f16(A1, bf[ty][j][1],   \
                                                              t0, 0, 0, 0);      \
        }                                                                         \
    }

#define SELECT_ACT(Z, TV, CC, HBUF)                                               \
    {                                                                             \
        float g4[4];                                                              \
        _Pragma("unroll")                                                         \
        for (int ty = 0; ty < 4; ++ty) {                                          \
            float s01 = (q & 1) ? Z[ty][1][0] : Z[ty][0][0];                      \
            float s23 = (q & 1) ? Z[ty][3][0] : Z[ty][2][0];                      \
            g4[ty] = (q & 2) ? s23 : s01;                                         \
        }                                                                         \
        float iv = sigm(g4[0] + h2f(TV.x));                                       \
        float fv = sigm(g4[1] + h2f(TV.y));                                       \
        float gv = tanh_(g4[2] + h2f(TV.z));                                      \
        float ov = sigm(g4[3] + h2f(TV.w));                                       \
        CC = fv * CC + iv * gv;                                                   \
        float hh = ov * tanh_(CC);                                                \
        HBUF[l] = f16b(hh);                                                       \
    }

// 1024 blocks x 64 threads: ONE WAVE drives TWO batch rows (P = 2b, Q = 2b+1)
// as software-pipelined chains in antiphase. No barriers / global loads in the
// step loop; each MFMA set has the other chain's act as covering work.
__global__ __launch_bounds__(64, 1) void lstm_wave2(
    const int*     __restrict__ x,
    const ushort*  __restrict__ Bmat,
    const ushort4* __restrict__ Ttg,
    const float*   __restrict__ W1,
    const float*   __restrict__ b1,
    const float*   __restrict__ W2,
    const float*   __restrict__ b2,
    float*         __restrict__ out)
{
    const int l   = threadIdx.x;    // lane = hidden unit u
    const int q   = l >> 4;
    const int c16 = l & 15;

    __shared__ __align__(16) ushort  hP[KPAD], hQ[KPAD];
    __shared__ __align__(16) int     xsP[T_SEQ + 8], xsQ[T_SEQ + 8];
    __shared__ __align__(16) ushort4 Tl[VOC * UPAD];

    // B fragments: MFMA-only operands -> AGPR-homed for free (no per-use moves)
    half8 bf[4][4][2];
    #pragma unroll
    for (int ty = 0; ty < 4; ++ty)
        #pragma unroll
        for (int j = 0; j < 4; ++j)
            #pragma unroll
            for (int kf = 0; kf < 2; ++kf) {
                int n = ty * UPAD + j * 16 + c16;
                bf[ty][j][kf] = *(const half8*)(Bmat + n * KPAD + kf * 32 + q * 8);
            }

    // preload tokens (both rows) + T-table; init h
    {
        const int4* xgP = (const int4*)(x + (long)(2 * blockIdx.x) * T_SEQ);
        const int4* xgQ = (const int4*)(x + (long)(2 * blockIdx.x + 1) * T_SEQ);
        #pragma unroll
        for (int i = 0; i < T_SEQ / 4 / 64; ++i) {       // 8 iterations each
            ((int4*)xsP)[l + i * 64] = xgP[l + i * 64];
            ((int4*)xsQ)[l + i * 64] = xgQ[l + i * 64];
        }
        for (int i = l; i < VOC * UPAD; i += 64)
            Tl[i] = Ttg[i];
        if (l == 0) { xsP[T_SEQ] = 0; xsQ[T_SEQ] = 0; }
        hP[l] = 0; hQ[l] = 0;
    }
    __syncthreads();     // once, outside the loop

    f32x4 zc = {0.f, 0.f, 0.f, 0.f};
    asm volatile("" : "+v"(zc));

    float cP = 0.f, cQ = 0.f;
    int tokP = xsP[0], tokQ = xsQ[0];
    ushort4 tvP = Tl[tokP * UPAD + l];
    ushort4 tvQ = Tl[tokQ * UPAD + l];

    half8 aP0 = *(const half8*)(hP + q * 8);
    half8 aP1 = *(const half8*)(hP + 32 + q * 8);
    half8 aQ0 = *(const half8*)(hQ + q * 8);
    half8 aQ1 = *(const half8*)(hQ + 32 + q * 8);

    f32x4 zP[4][4], zQ[4][4];
    ISSUE_MFMA(zP, aP0, aP1)                 // pre-issue P(0)

    for (int s = 0; s < T_SEQ; ++s) {
        ISSUE_MFMA(zQ, aQ0, aQ1)            // (1) Q(s) in flight over P's act

        SELECT_ACT(zP, tvP, cP, hP)         // (2) act P(s) -> h_P(s+1)
        tokP = xsP[s + 1];
        aP0 = *(const half8*)(hP + q * 8);
        aP1 = *(const half8*)(hP + 32 + q * 8);
        tvP = Tl[tokP * UPAD + l];

        SELECT_ACT(zQ, tvQ, cQ, hQ)         // (4) act Q(s) -> h_Q(s+1)
        tokQ = xsQ[s + 1];
        aQ0 = *(const half8*)(hQ + q * 8);
        aQ1 = *(const half8*)(hQ + 32 + q * 8);
        tvQ = Tl[tokQ * UPAD + l];

        ISSUE_MFMA(zP, aP0, aP1)            // (3) P(s+1) in flight over Q's act
    }
    // (final extra MFMA issue is harmless; all reads in-bounds)

    // epilogue MLP for both rows (same-wave, DS in-order, no barriers needed)
    float* RfP = (float*)xsP;               // reuse LDS
    float* RfQ = (float*)xsQ;
    if (l < HID) {
        float a = b1[l], b = b1[l];
        #pragma unroll 10
        for (int k = 0; k < HID; ++k) {
            a = fmaf(W1[l * HID + k], h2f(hP[k]), a);
            b = fmaf(W1[l * HID + k], h2f(hQ[k]), b);
        }
        RfP[l] = fmaxf(a, 0.f);
        RfQ[l] = fmaxf(b, 0.f);
    }
    if (l == 0) {
        float a = b2[0], b = b2[0];
        #pragma unroll 10
        for (int j = 0; j < HID; ++j) {
            a = fmaf(W2[j], RfP[j], a);
            b = fmaf(W2[j], RfQ[j], b);
        }
        out[2 * blockIdx.x]     = a;
        out[2 * blockIdx.x + 1] = b;
    }
}

extern "C" void kernel_launch(void* const* d_in, const int* in_sizes, int n_in,
                              void* d_out, int out_size, void* d_ws, size_t ws_size,
                              hipStream_t stream) {
    const int*   x     = (const int*)  d_in[0];
    const float* embed = (const float*)d_in[1];
    const float* W_ih  = (const float*)d_in[2];
    const float* W_hh  = (const float*)d_in[3];
    const float* b_ih  = (const float*)d_in[4];
    const float* b_hh  = (const float*)d_in[5];
    const float* W1    = (const float*)d_in[6];
    const float* b1    = (const float*)d_in[7];
    const float* W2    = (const float*)d_in[8];
    const float* b2    = (const float*)d_in[9];
    float* out = (float*)d_out;

    ushort*  Bmat = (ushort*)d_ws;                              // 32 KB
    ushort4* Ttg  = (ushort4*)((char*)d_ws + NPAD * KPAD * 2);  // 6.7 KB

    build_B<<<(NPAD * KPAD + 255) / 256, 256, 0, stream>>>(W_hh, Bmat);
    build_T<<<(VOC * UPAD + 255) / 256, 256, 0, stream>>>(embed, W_ih, b_ih, b_hh, Ttg);

    lstm_wave2<<<NBLK, 64, 0, stream>>>(x, Bmat, Ttg, W1, b1, W2, b2, out);
}